// Round 1
// baseline (415.635 us; speedup 1.0000x reference)
//
#include <hip/hip_runtime.h>

#define DEV __device__ __forceinline__

typedef __attribute__((ext_vector_type(4))) float f32x4;
typedef __attribute__((ext_vector_type(4))) float fl4;
typedef __attribute__((ext_vector_type(8))) __bf16 bf16x8;
typedef __attribute__((ext_vector_type(4))) unsigned short us4;
typedef __attribute__((ext_vector_type(8))) unsigned short us8;

static constexpr int Nn = 2048, Hh = 16;

DEV unsigned short f2bf(float f) {
  unsigned u = __builtin_bit_cast(unsigned, f);
  u += 0x7fffu + ((u >> 16) & 1u);
  return (unsigned short)(u >> 16);
}
DEV float bf2f(unsigned short h) {
  unsigned u = ((unsigned)h) << 16;
  return __builtin_bit_cast(float, u);
}

DEV void load_lds16(const void* g, void* l) {
  __builtin_amdgcn_global_load_lds(
      (const __attribute__((address_space(1))) void*)g,
      (__attribute__((address_space(3))) void*)l, 16, 0, 0);
}

// ---------------- convert x -> bf16 ----------------
__global__ void k_convert_x(const float* __restrict__ x, unsigned short* __restrict__ xb) {
  size_t i = (size_t)blockIdx.x * 256 + threadIdx.x;  // one 8-elem chunk each
  const float* p = x + i * 8;
  fl4 a = *(const fl4*)p;
  fl4 b = *(const fl4*)(p + 4);
  us8 o;
  o[0] = f2bf(a[0]); o[1] = f2bf(a[1]); o[2] = f2bf(a[2]); o[3] = f2bf(a[3]);
  o[4] = f2bf(b[0]); o[5] = f2bf(b[1]); o[6] = f2bf(b[2]); o[7] = f2bf(b[3]);
  *(us8*)(xb + i * 8) = o;
}

// ---------------- weight transpose -> bf16 (W is KxN row-major; T is NxK) ----
__global__ void k_transw(const float* __restrict__ W0, const float* __restrict__ W1,
                         const float* __restrict__ W2, const float* __restrict__ W3,
                         unsigned short* __restrict__ T0, unsigned short* __restrict__ T1,
                         unsigned short* __restrict__ T2, unsigned short* __restrict__ T3) {
  const float* W; unsigned short* T;
  switch (blockIdx.y) {
    case 0: W = W0; T = T0; break;
    case 1: W = W1; T = T1; break;
    case 2: W = W2; T = T2; break;
    default: W = W3; T = T3; break;
  }
  __shared__ float tile[64][65];
  int k0 = (blockIdx.x >> 4) * 64, n0 = (blockIdx.x & 15) * 64;
  int tr = threadIdx.x >> 4, tc = (threadIdx.x & 15) * 4;
#pragma unroll
  for (int p = 0; p < 4; ++p) {
    int r = p * 16 + tr;
    fl4 v = *(const fl4*)&W[(size_t)(k0 + r) * 1024 + n0 + tc];
#pragma unroll
    for (int j = 0; j < 4; ++j) tile[r][tc + j] = v[j];
  }
  __syncthreads();
#pragma unroll
  for (int p = 0; p < 4; ++p) {
    int rr = p * 16 + tr;  // output row (n index)
    us4 o;
#pragma unroll
    for (int j = 0; j < 4; ++j) o[j] = f2bf(tile[tc + j][rr]);
    *(us4*)&T[(size_t)(n0 + rr) * 1024 + k0 + tc] = o;
  }
}

// ---------------- GEMM: C(8192x1024) = A(8192x1024,bf16) * Bt(1024x1024,bf16)^T + bias
// MODE 0: bf16 row-major out.  MODE 1: bf16 transposed out (Vt[b][hd][seq]).  MODE 2: fp32 out.
template <int MODE>
__global__ __launch_bounds__(256, 2) void k_gemm(const unsigned short* __restrict__ A,
                                                 const unsigned short* __restrict__ Bt,
                                                 const float* __restrict__ bias,
                                                 void* __restrict__ Cout) {
  __shared__ alignas(16) unsigned short As[4096];  // [g:4][row:128][8]
  __shared__ alignas(16) unsigned short Bs[4096];
  int tid = threadIdx.x, w = tid >> 6, l = tid & 63;
  int lg = l >> 4, lm = l & 15;
  int bm = blockIdx.x >> 3, bn = blockIdx.x & 7;
  int wr = w >> 1, wc = w & 1;
  f32x4 acc[4][4] = {};
  for (int kt = 0; kt < 32; ++kt) {
    int k0 = kt * 32;
#pragma unroll
    for (int p = 0; p < 2; ++p) {
      int cb = (w * 2 + p) * 64;
      int c = cb + l;
      int g = c >> 7, r = c & 127;
      load_lds16(A + (size_t)(bm * 128 + r) * 1024 + k0 + g * 8, As + (size_t)cb * 8);
      load_lds16(Bt + (size_t)(bn * 128 + r) * 1024 + k0 + g * 8, Bs + (size_t)cb * 8);
    }
    __syncthreads();
    bf16x8 af[4], bfr[4];
#pragma unroll
    for (int m = 0; m < 4; ++m)
      af[m] = *(const bf16x8*)&As[(lg * 128 + wr * 64 + m * 16 + lm) * 8];
#pragma unroll
    for (int n = 0; n < 4; ++n)
      bfr[n] = *(const bf16x8*)&Bs[(lg * 128 + wc * 64 + n * 16 + lm) * 8];
#pragma unroll
    for (int m = 0; m < 4; ++m)
#pragma unroll
      for (int n = 0; n < 4; ++n)
        acc[m][n] = __builtin_amdgcn_mfma_f32_16x16x32_bf16(af[m], bfr[n], acc[m][n], 0, 0, 0);
    __syncthreads();
  }
  int row0 = bm * 128 + wr * 64, col0 = bn * 128 + wc * 64;
  if (MODE == 0) {
    unsigned short* C = (unsigned short*)Cout;
#pragma unroll
    for (int n = 0; n < 4; ++n) {
      int col = col0 + n * 16 + lm;
      float bv = bias[col];
#pragma unroll
      for (int m = 0; m < 4; ++m) {
        int row = row0 + m * 16 + lg * 4;
#pragma unroll
        for (int i = 0; i < 4; ++i)
          C[(size_t)(row + i) * 1024 + col] = f2bf(acc[m][n][i] + bv);
      }
    }
  } else if (MODE == 1) {
    unsigned short* Vt = (unsigned short*)Cout;
#pragma unroll
    for (int n = 0; n < 4; ++n) {
      int col = col0 + n * 16 + lm;  // h*64+d
      float bv = bias[col];
#pragma unroll
      for (int m = 0; m < 4; ++m) {
        int row = row0 + m * 16 + lg * 4;  // global seq row (b*2048+s)
        int bb = row >> 11, s = row & 2047;
        us4 o;
#pragma unroll
        for (int i = 0; i < 4; ++i) o[i] = f2bf(acc[m][n][i] + bv);
        *(us4*)&Vt[((size_t)(bb * 1024 + col)) * 2048 + s] = o;
      }
    }
  } else {
    float* C = (float*)Cout;
#pragma unroll
    for (int n = 0; n < 4; ++n) {
      int col = col0 + n * 16 + lm;
      float bv = bias[col];
#pragma unroll
      for (int m = 0; m < 4; ++m) {
        int row = row0 + m * 16 + lg * 4;
#pragma unroll
        for (int i = 0; i < 4; ++i)
          C[(size_t)(row + i) * 1024 + col] = acc[m][n][i] + bv;
      }
    }
  }
}

// ---------------- RoPE in-place on bf16 (b*2048+s, 1024) layout; scale folds 1/sqrt(D) into Q
__global__ void k_rope(unsigned short* __restrict__ X, float scale) {
  int p = blockIdx.x * 256 + threadIdx.x;  // pair index, 8192*512 total
  int m = p >> 9, cp = p & 511;
  int t = cp & 31;         // pair index within head (d = 2t, 2t+1)
  int pos = m & 2047;
  // theta^(-2t/64) = exp2(-t/32 * log2(10000))
  float ang = (float)pos * exp2f(-(float)t * 0.41524101186092029f);
  float sn, cs;
  __sincosf(ang, &sn, &cs);
  unsigned* q = (unsigned*)(X + (size_t)m * 1024 + cp * 2);
  unsigned v = *q;
  float x1 = bf2f((unsigned short)(v & 0xffffu));
  float x2 = bf2f((unsigned short)(v >> 16));
  float o1 = (x1 * cs - x2 * sn) * scale;
  float o2 = (x2 * cs + x1 * sn) * scale;
  *q = ((unsigned)f2bf(o2) << 16) | f2bf(o1);
}

// ---------------- flash attention ----------------
// Q,K: (b*2048+s, h*64+d) bf16 (Q pre-scaled by 1/32). Vt: [b][h*64+d][s] bf16.
// Out: (b*2048+s, h*64+d) bf16.
__global__ __launch_bounds__(256, 2) void k_attn(const unsigned short* __restrict__ Q,
                                                 const unsigned short* __restrict__ K,
                                                 const unsigned short* __restrict__ Vt,
                                                 unsigned short* __restrict__ O) {
  __shared__ alignas(16) unsigned short Ks[4096];        // [g:8][key:64][8]  (8 d-values per chunk)
  __shared__ alignas(16) unsigned short Vs[4096];        // [g:8][d:64][8]    (8 j-values per chunk)
  __shared__ alignas(16) unsigned short Ps[4][16][72];   // per-wave P tile, 144B rows (9x16B)
  int tid = threadIdx.x, w = tid >> 6, l = tid & 63;
  int lg = l >> 4, lm = l & 15;
  int bid = blockIdx.x;
  int qt = bid & 31, h = (bid >> 5) & 15, b = bid >> 9;
  int qrow0 = qt * 64 + w * 16;

  const unsigned short* qp = Q + (size_t)(b * 2048 + qrow0 + lm) * 1024 + h * 64 + lg * 8;
  bf16x8 qf0 = *(const bf16x8*)qp;
  bf16x8 qf1 = *(const bf16x8*)(qp + 32);

  float M[4], L[4];
  f32x4 Oa[4] = {};
#pragma unroll
  for (int i = 0; i < 4; ++i) { M[i] = -1e30f; L[i] = 0.0f; }

  for (int kt = 0; kt < 32; ++kt) {
    int j0 = kt * 64;
#pragma unroll
    for (int p = 0; p < 2; ++p) {
      int cb = (w * 2 + p) * 64;
      int c = cb + l;
      int g = c >> 6, r = c & 63;
      load_lds16(K + (size_t)(b * 2048 + j0 + r) * 1024 + h * 64 + g * 8, Ks + (size_t)cb * 8);
      load_lds16(Vt + ((size_t)((b * 16 + h) * 64 + r)) * 2048 + j0 + g * 8, Vs + (size_t)cb * 8);
    }
    __syncthreads();
    // S = Q * K^T  (rows: 16 q, cols: 64 keys in 4 blocks)
    f32x4 s[4];
#pragma unroll
    for (int c = 0; c < 4; ++c) {
      bf16x8 kf0 = *(const bf16x8*)&Ks[((lg)*64 + c * 16 + lm) * 8];
      bf16x8 kf1 = *(const bf16x8*)&Ks[((lg + 4) * 64 + c * 16 + lm) * 8];
      f32x4 z = {};
      z = __builtin_amdgcn_mfma_f32_16x16x32_bf16(qf0, kf0, z, 0, 0, 0);
      s[c] = __builtin_amdgcn_mfma_f32_16x16x32_bf16(qf1, kf1, z, 0, 0, 0);
    }
    // online softmax: rows are (lg*4+i), cols spread over lm and c
    float mx[4], ls[4], nm[4], sc[4], pv[4][4];
#pragma unroll
    for (int i = 0; i < 4; ++i)
      mx[i] = fmaxf(fmaxf(s[0][i], s[1][i]), fmaxf(s[2][i], s[3][i]));
#pragma unroll
    for (int d = 1; d < 16; d <<= 1)
#pragma unroll
      for (int i = 0; i < 4; ++i) mx[i] = fmaxf(mx[i], __shfl_xor(mx[i], d, 64));
#pragma unroll
    for (int i = 0; i < 4; ++i) {
      nm[i] = fmaxf(M[i], mx[i]);
      sc[i] = exp2f((M[i] - nm[i]) * 1.4426950408889634f);
    }
#pragma unroll
    for (int c = 0; c < 4; ++c)
#pragma unroll
      for (int i = 0; i < 4; ++i)
        pv[c][i] = exp2f((s[c][i] - nm[i]) * 1.4426950408889634f);
#pragma unroll
    for (int i = 0; i < 4; ++i) ls[i] = pv[0][i] + pv[1][i] + pv[2][i] + pv[3][i];
#pragma unroll
    for (int d = 1; d < 16; d <<= 1)
#pragma unroll
      for (int i = 0; i < 4; ++i) ls[i] += __shfl_xor(ls[i], d, 64);
#pragma unroll
    for (int i = 0; i < 4; ++i) { L[i] = L[i] * sc[i] + ls[i]; M[i] = nm[i]; }
#pragma unroll
    for (int n = 0; n < 4; ++n)
#pragma unroll
      for (int i = 0; i < 4; ++i) Oa[n][i] *= sc[i];
    // P -> LDS (acc layout) then reload as A-fragments
#pragma unroll
    for (int c = 0; c < 4; ++c)
#pragma unroll
      for (int i = 0; i < 4; ++i)
        Ps[w][lg * 4 + i][c * 16 + lm] = f2bf(pv[c][i]);
    asm volatile("s_waitcnt lgkmcnt(0)" ::: "memory");
    bf16x8 pa0 = *(const bf16x8*)&Ps[w][lm][lg * 8];
    bf16x8 pa1 = *(const bf16x8*)&Ps[w][lm][32 + lg * 8];
#pragma unroll
    for (int n = 0; n < 4; ++n) {
      bf16x8 vf0 = *(const bf16x8*)&Vs[((lg)*64 + n * 16 + lm) * 8];
      bf16x8 vf1 = *(const bf16x8*)&Vs[((lg + 4) * 64 + n * 16 + lm) * 8];
      Oa[n] = __builtin_amdgcn_mfma_f32_16x16x32_bf16(pa0, vf0, Oa[n], 0, 0, 0);
      Oa[n] = __builtin_amdgcn_mfma_f32_16x16x32_bf16(pa1, vf1, Oa[n], 0, 0, 0);
    }
    __syncthreads();
  }
  float inv[4];
#pragma unroll
  for (int i = 0; i < 4; ++i) inv[i] = 1.0f / L[i];
#pragma unroll
  for (int n = 0; n < 4; ++n) {
    int col = h * 64 + n * 16 + lm;
#pragma unroll
    for (int i = 0; i < 4; ++i) {
      int row = qrow0 + lg * 4 + i;
      O[(size_t)(b * 2048 + row) * 1024 + col] = f2bf(Oa[n][i] * inv[i]);
    }
  }
}

extern "C" void kernel_launch(void* const* d_in, const int* in_sizes, int n_in,
                              void* d_out, int out_size, void* d_ws, size_t ws_size,
                              hipStream_t stream) {
  const float* x  = (const float*)d_in[0];
  const float* Wq = (const float*)d_in[1];
  const float* bq = (const float*)d_in[2];
  const float* Wk = (const float*)d_in[3];
  const float* bk = (const float*)d_in[4];
  const float* Wv = (const float*)d_in[5];
  const float* bv = (const float*)d_in[6];
  const float* Wo = (const float*)d_in[7];
  const float* bo = (const float*)d_in[8];
  float* out = (float*)d_out;

  // workspace layout (all bf16 = ushort). total = 92.3 MB
  unsigned short* xb  = (unsigned short*)d_ws;           // 8192x1024
  unsigned short* WqT = xb + (size_t)8192 * 1024;        // 1024x1024 each
  unsigned short* WkT = WqT + (size_t)1024 * 1024;
  unsigned short* WvT = WkT + (size_t)1024 * 1024;
  unsigned short* WoT = WvT + (size_t)1024 * 1024;
  unsigned short* Qb  = WoT + (size_t)1024 * 1024;       // 8192x1024
  unsigned short* Kb  = Qb + (size_t)8192 * 1024;
  unsigned short* Vt  = Kb + (size_t)8192 * 1024;        // [b][h*64+d][2048]
  unsigned short* Ib  = Vt + (size_t)8192 * 1024;        // attention out, 8192x1024

  k_convert_x<<<4096, 256, 0, stream>>>(x, xb);
  k_transw<<<dim3(256, 4), 256, 0, stream>>>(Wq, Wk, Wv, Wo, WqT, WkT, WvT, WoT);
  k_gemm<0><<<512, 256, 0, stream>>>(xb, WqT, bq, (void*)Qb);
  k_gemm<0><<<512, 256, 0, stream>>>(xb, WkT, bk, (void*)Kb);
  k_gemm<1><<<512, 256, 0, stream>>>(xb, WvT, bv, (void*)Vt);
  k_rope<<<16384, 256, 0, stream>>>(Qb, 1.0f / 32.0f);
  k_rope<<<16384, 256, 0, stream>>>(Kb, 1.0f);
  k_attn<<<2048, 256, 0, stream>>>(Qb, Kb, Vt, Ib);
  k_gemm<2><<<512, 256, 0, stream>>>(Ib, WoT, bo, d_out);
}

// Round 2
// 318.673 us; speedup vs baseline: 1.3043x; 1.3043x over previous
//
#include <hip/hip_runtime.h>

#define DEV __device__ __forceinline__

typedef __attribute__((ext_vector_type(4))) float f32x4;
typedef __attribute__((ext_vector_type(16))) float f32x16;
typedef __attribute__((ext_vector_type(4))) float fl4;
typedef __attribute__((ext_vector_type(8))) __bf16 bf16x8;
typedef __attribute__((ext_vector_type(2))) __bf16 bf16x2;
typedef __attribute__((ext_vector_type(4))) unsigned short us4;
typedef __attribute__((ext_vector_type(8))) unsigned short us8;
typedef __attribute__((ext_vector_type(4))) unsigned int ui4;

DEV unsigned short f2bf(float f) {
  unsigned u = __builtin_bit_cast(unsigned, f);
  u += 0x7fffu + ((u >> 16) & 1u);
  return (unsigned short)(u >> 16);
}
DEV float bf2f(unsigned short h) {
  unsigned u = ((unsigned)h) << 16;
  return __builtin_bit_cast(float, u);
}

DEV void load_lds16(const void* g, void* l) {
  __builtin_amdgcn_global_load_lds(
      (const __attribute__((address_space(1))) void*)g,
      (__attribute__((address_space(3))) void*)l, 16, 0, 0);
}

DEV unsigned pk2(float a, float b) {  // pack 2 fp32 -> 2 bf16 (RNE, v_cvt_pk_bf16_f32)
  bf16x2 t;
  t[0] = (__bf16)a; t[1] = (__bf16)b;
  return __builtin_bit_cast(unsigned, t);
}
DEV bf16x8 frag4(unsigned a, unsigned b, unsigned c, unsigned d) {
  ui4 u; u[0] = a; u[1] = b; u[2] = c; u[3] = d;
  return __builtin_bit_cast(bf16x8, u);
}

// ---------------- convert x -> bf16 ----------------
__global__ void k_convert_x(const float* __restrict__ x, unsigned short* __restrict__ xb) {
  size_t i = (size_t)blockIdx.x * 256 + threadIdx.x;
  const float* p = x + i * 8;
  fl4 a = *(const fl4*)p;
  fl4 b = *(const fl4*)(p + 4);
  us8 o;
  o[0] = f2bf(a[0]); o[1] = f2bf(a[1]); o[2] = f2bf(a[2]); o[3] = f2bf(a[3]);
  o[4] = f2bf(b[0]); o[5] = f2bf(b[1]); o[6] = f2bf(b[2]); o[7] = f2bf(b[3]);
  *(us8*)(xb + i * 8) = o;
}

// ---------------- weight transpose -> bf16 ----------------
__global__ void k_transw(const float* __restrict__ W0, const float* __restrict__ W1,
                         const float* __restrict__ W2, const float* __restrict__ W3,
                         unsigned short* __restrict__ T0, unsigned short* __restrict__ T1,
                         unsigned short* __restrict__ T2, unsigned short* __restrict__ T3) {
  const float* W; unsigned short* T;
  switch (blockIdx.y) {
    case 0: W = W0; T = T0; break;
    case 1: W = W1; T = T1; break;
    case 2: W = W2; T = T2; break;
    default: W = W3; T = T3; break;
  }
  __shared__ float tile[64][65];
  int k0 = (blockIdx.x >> 4) * 64, n0 = (blockIdx.x & 15) * 64;
  int tr = threadIdx.x >> 4, tc = (threadIdx.x & 15) * 4;
#pragma unroll
  for (int p = 0; p < 4; ++p) {
    int r = p * 16 + tr;
    fl4 v = *(const fl4*)&W[(size_t)(k0 + r) * 1024 + n0 + tc];
#pragma unroll
    for (int j = 0; j < 4; ++j) tile[r][tc + j] = v[j];
  }
  __syncthreads();
#pragma unroll
  for (int p = 0; p < 4; ++p) {
    int rr = p * 16 + tr;
    us4 o;
#pragma unroll
    for (int j = 0; j < 4; ++j) o[j] = f2bf(tile[tc + j][rr]);
    *(us4*)&T[(size_t)(n0 + rr) * 1024 + k0 + tc] = o;
  }
}

// ---------------- GEMM (unchanged from round 1) ----------------
template <int MODE>
__global__ __launch_bounds__(256, 2) void k_gemm(const unsigned short* __restrict__ A,
                                                 const unsigned short* __restrict__ Bt,
                                                 const float* __restrict__ bias,
                                                 void* __restrict__ Cout) {
  __shared__ alignas(16) unsigned short As[4096];
  __shared__ alignas(16) unsigned short Bs[4096];
  int tid = threadIdx.x, w = tid >> 6, l = tid & 63;
  int lg = l >> 4, lm = l & 15;
  int bm = blockIdx.x >> 3, bn = blockIdx.x & 7;
  int wr = w >> 1, wc = w & 1;
  f32x4 acc[4][4] = {};
  for (int kt = 0; kt < 32; ++kt) {
    int k0 = kt * 32;
#pragma unroll
    for (int p = 0; p < 2; ++p) {
      int cb = (w * 2 + p) * 64;
      int c = cb + l;
      int g = c >> 7, r = c & 127;
      load_lds16(A + (size_t)(bm * 128 + r) * 1024 + k0 + g * 8, As + (size_t)cb * 8);
      load_lds16(Bt + (size_t)(bn * 128 + r) * 1024 + k0 + g * 8, Bs + (size_t)cb * 8);
    }
    __syncthreads();
    bf16x8 af[4], bfr[4];
#pragma unroll
    for (int m = 0; m < 4; ++m)
      af[m] = *(const bf16x8*)&As[(lg * 128 + wr * 64 + m * 16 + lm) * 8];
#pragma unroll
    for (int n = 0; n < 4; ++n)
      bfr[n] = *(const bf16x8*)&Bs[(lg * 128 + wc * 64 + n * 16 + lm) * 8];
#pragma unroll
    for (int m = 0; m < 4; ++m)
#pragma unroll
      for (int n = 0; n < 4; ++n)
        acc[m][n] = __builtin_amdgcn_mfma_f32_16x16x32_bf16(af[m], bfr[n], acc[m][n], 0, 0, 0);
    __syncthreads();
  }
  int row0 = bm * 128 + wr * 64, col0 = bn * 128 + wc * 64;
  if (MODE == 0) {
    unsigned short* C = (unsigned short*)Cout;
#pragma unroll
    for (int n = 0; n < 4; ++n) {
      int col = col0 + n * 16 + lm;
      float bv = bias[col];
#pragma unroll
      for (int m = 0; m < 4; ++m) {
        int row = row0 + m * 16 + lg * 4;
#pragma unroll
        for (int i = 0; i < 4; ++i)
          C[(size_t)(row + i) * 1024 + col] = f2bf(acc[m][n][i] + bv);
      }
    }
  } else if (MODE == 1) {
    unsigned short* Vt = (unsigned short*)Cout;
#pragma unroll
    for (int n = 0; n < 4; ++n) {
      int col = col0 + n * 16 + lm;
      float bv = bias[col];
#pragma unroll
      for (int m = 0; m < 4; ++m) {
        int row = row0 + m * 16 + lg * 4;
        int bb = row >> 11, s = row & 2047;
        us4 o;
#pragma unroll
        for (int i = 0; i < 4; ++i) o[i] = f2bf(acc[m][n][i] + bv);
        *(us4*)&Vt[((size_t)(bb * 1024 + col)) * 2048 + s] = o;
      }
    }
  } else {
    float* C = (float*)Cout;
#pragma unroll
    for (int n = 0; n < 4; ++n) {
      int col = col0 + n * 16 + lm;
      float bv = bias[col];
#pragma unroll
      for (int m = 0; m < 4; ++m) {
        int row = row0 + m * 16 + lg * 4;
#pragma unroll
        for (int i = 0; i < 4; ++i)
          C[(size_t)(row + i) * 1024 + col] = acc[m][n][i] + bv;
      }
    }
  }
}

// ---------------- RoPE (unchanged) ----------------
__global__ void k_rope(unsigned short* __restrict__ X, float scale) {
  int p = blockIdx.x * 256 + threadIdx.x;
  int m = p >> 9, cp = p & 511;
  int t = cp & 31;
  int pos = m & 2047;
  float ang = (float)pos * exp2f(-(float)t * 0.41524101186092029f);
  float sn, cs;
  __sincosf(ang, &sn, &cs);
  unsigned* q = (unsigned*)(X + (size_t)m * 1024 + cp * 2);
  unsigned v = *q;
  float x1 = bf2f((unsigned short)(v & 0xffffu));
  float x2 = bf2f((unsigned short)(v >> 16));
  float o1 = (x1 * cs - x2 * sn) * scale;
  float o2 = (x2 * cs + x1 * sn) * scale;
  *q = ((unsigned)f2bf(o2) << 16) | f2bf(o1);
}

// ---------------- flash attention, 32x32 swapped-operand structure ----------------
// Q,K: (b*2048+s, h*64+d) bf16 (Q pre-scaled 1/32). Vt: [b][h*64+d][s] bf16.
// Per wave: 32 q-rows. S = mfma(K, Q) -> S[key][query], query = lane&31 (lane-owned row).
// PV as O^T = mfma(V^T, P) -> O^T[d][query], query = lane&31 again -> scalar M/L/rescale.
// K/V staged fragment-ordered + lane-linear in LDS (per-lane global src, linear dest):
// zero bank conflicts, no swizzle needed.
__global__ __launch_bounds__(256, 3) void k_attn(const unsigned short* __restrict__ Q,
                                                 const unsigned short* __restrict__ K,
                                                 const unsigned short* __restrict__ Vt,
                                                 unsigned short* __restrict__ O) {
  __shared__ alignas(16) unsigned short Ks[2][4096];  // [g=kb*4+dc][lane][8]
  __shared__ alignas(16) unsigned short Vs[2][4096];  // [g=m*2+cb][lane][8]
  const int tid = threadIdx.x, w = tid >> 6, l = tid & 63;
  const int lq = l & 31, hi = l >> 5;
  const int bid = blockIdx.x;
  const int qt = bid & 15, h = (bid >> 4) & 15, b = bid >> 8;
  const int qrow = qt * 128 + w * 32 + lq;

  // Q row of this lane's query, as 4 B-fragments (k = dc*16 + hi*8 + e)
  const unsigned short* qp = Q + ((size_t)(b * 2048 + qrow)) * 1024 + h * 64 + hi * 8;
  bf16x8 qf[4];
#pragma unroll
  for (int dc = 0; dc < 4; ++dc) qf[dc] = *(const bf16x8*)(qp + dc * 16);

  const unsigned short* Kbase = K + ((size_t)(b * 2048)) * 1024 + h * 64;
  const unsigned short* Vbase = Vt + ((size_t)((b * 16 + h) * 64)) * 2048;

  float M = -1e30f, L = 0.0f;
  f32x16 Oa0 = {}, Oa1 = {};

  // stage tile 0
#pragma unroll
  for (int c = tid; c < 512; c += 256) {
    int g = c >> 6, ll = c & 63;
    load_lds16(Kbase + ((size_t)((g >> 2) * 32 + (ll & 31))) * 1024 + (g & 3) * 16 + (ll >> 5) * 8,
               &Ks[0][c * 8]);
    load_lds16(Vbase + ((size_t)((g & 1) * 32 + (ll & 31))) * 2048 + (g >> 1) * 16 + (ll >> 5) * 8,
               &Vs[0][c * 8]);
  }
  __syncthreads();  // drains vmcnt

  for (int t = 0; t < 32; ++t) {
    const int cur = t & 1;
    if (t + 1 < 32) {
      const int j1 = (t + 1) * 64;
#pragma unroll
      for (int c = tid; c < 512; c += 256) {
        int g = c >> 6, ll = c & 63;
        load_lds16(Kbase + ((size_t)(j1 + (g >> 2) * 32 + (ll & 31))) * 1024 + (g & 3) * 16 + (ll >> 5) * 8,
                   &Ks[cur ^ 1][c * 8]);
        load_lds16(Vbase + ((size_t)((g & 1) * 32 + (ll & 31))) * 2048 + j1 + (g >> 1) * 16 + (ll >> 5) * 8,
                   &Vs[cur ^ 1][c * 8]);
      }
    }
    // S[key][query] for 2 key-blocks of 32
    f32x16 s0 = {}, s1 = {};
#pragma unroll
    for (int dc = 0; dc < 4; ++dc) {
      bf16x8 kf0 = *(const bf16x8*)&Ks[cur][(dc * 64 + l) * 8];
      bf16x8 kf1 = *(const bf16x8*)&Ks[cur][((4 + dc) * 64 + l) * 8];
      s0 = __builtin_amdgcn_mfma_f32_32x32x16_bf16(kf0, qf[dc], s0, 0, 0, 0);
      s1 = __builtin_amdgcn_mfma_f32_32x32x16_bf16(kf1, qf[dc], s1, 0, 0, 0);
    }
    // online softmax: lane owns query lq; keys split between lane and lane^32
    float mx = s0[0];
#pragma unroll
    for (int r = 1; r < 16; ++r) mx = fmaxf(mx, s0[r]);
#pragma unroll
    for (int r = 0; r < 16; ++r) mx = fmaxf(mx, s1[r]);
    mx = fmaxf(mx, __shfl_xor(mx, 32, 64));
    const float nm = fmaxf(M, mx);
    const float sc = exp2f((M - nm) * 1.4426950408889634f);
    float p0[16], p1[16], ls = 0.0f;
#pragma unroll
    for (int r = 0; r < 16; ++r) { p0[r] = exp2f((s0[r] - nm) * 1.4426950408889634f); ls += p0[r]; }
#pragma unroll
    for (int r = 0; r < 16; ++r) { p1[r] = exp2f((s1[r] - nm) * 1.4426950408889634f); ls += p1[r]; }
    ls += __shfl_xor(ls, 32, 64);
    L = L * sc + ls;
    M = nm;
    Oa0 *= sc;
    Oa1 *= sc;
    // pack P to bf16 pairs; key(r,hi) = (r&3)+8*(r>>2)+4*hi, pairs (2j,2j+1) adjacent
    unsigned w0[8], w1[8];
#pragma unroll
    for (int j = 0; j < 8; ++j) {
      w0[j] = pk2(p0[2 * j], p0[2 * j + 1]);
      w1[j] = pk2(p1[2 * j], p1[2 * j + 1]);
    }
    // exchange halves with lane^32 to build B-frags (k = key = 16m + hi*8 + e)
    unsigned ra = __shfl_xor(hi ? w0[0] : w0[2], 32, 64);
    unsigned rb = __shfl_xor(hi ? w0[1] : w0[3], 32, 64);
    unsigned rc = __shfl_xor(hi ? w0[4] : w0[6], 32, 64);
    unsigned rd = __shfl_xor(hi ? w0[5] : w0[7], 32, 64);
    unsigned re = __shfl_xor(hi ? w1[0] : w1[2], 32, 64);
    unsigned rf = __shfl_xor(hi ? w1[1] : w1[3], 32, 64);
    unsigned rg = __shfl_xor(hi ? w1[4] : w1[6], 32, 64);
    unsigned rh = __shfl_xor(hi ? w1[5] : w1[7], 32, 64);
    bf16x8 pf0 = hi ? frag4(ra, rb, w0[2], w0[3]) : frag4(w0[0], w0[1], ra, rb);
    bf16x8 pf1 = hi ? frag4(rc, rd, w0[6], w0[7]) : frag4(w0[4], w0[5], rc, rd);
    bf16x8 pf2 = hi ? frag4(re, rf, w1[2], w1[3]) : frag4(w1[0], w1[1], re, rf);
    bf16x8 pf3 = hi ? frag4(rg, rh, w1[6], w1[7]) : frag4(w1[4], w1[5], rg, rh);
    // O^T[d][query] += V^T[d][key] * P[key][query]
    {
      bf16x8 v0 = *(const bf16x8*)&Vs[cur][((0 * 2 + 0) * 64 + l) * 8];
      bf16x8 v1 = *(const bf16x8*)&Vs[cur][((0 * 2 + 1) * 64 + l) * 8];
      Oa0 = __builtin_amdgcn_mfma_f32_32x32x16_bf16(v0, pf0, Oa0, 0, 0, 0);
      Oa1 = __builtin_amdgcn_mfma_f32_32x32x16_bf16(v1, pf0, Oa1, 0, 0, 0);
      v0 = *(const bf16x8*)&Vs[cur][((1 * 2 + 0) * 64 + l) * 8];
      v1 = *(const bf16x8*)&Vs[cur][((1 * 2 + 1) * 64 + l) * 8];
      Oa0 = __builtin_amdgcn_mfma_f32_32x32x16_bf16(v0, pf1, Oa0, 0, 0, 0);
      Oa1 = __builtin_amdgcn_mfma_f32_32x32x16_bf16(v1, pf1, Oa1, 0, 0, 0);
      v0 = *(const bf16x8*)&Vs[cur][((2 * 2 + 0) * 64 + l) * 8];
      v1 = *(const bf16x8*)&Vs[cur][((2 * 2 + 1) * 64 + l) * 8];
      Oa0 = __builtin_amdgcn_mfma_f32_32x32x16_bf16(v0, pf2, Oa0, 0, 0, 0);
      Oa1 = __builtin_amdgcn_mfma_f32_32x32x16_bf16(v1, pf2, Oa1, 0, 0, 0);
      v0 = *(const bf16x8*)&Vs[cur][((3 * 2 + 0) * 64 + l) * 8];
      v1 = *(const bf16x8*)&Vs[cur][((3 * 2 + 1) * 64 + l) * 8];
      Oa0 = __builtin_amdgcn_mfma_f32_32x32x16_bf16(v0, pf3, Oa0, 0, 0, 0);
      Oa1 = __builtin_amdgcn_mfma_f32_32x32x16_bf16(v1, pf3, Oa1, 0, 0, 0);
    }
    __syncthreads();  // drains vmcnt (next tile staged) + protects cur buffer
  }
  const float inv = 1.0f / L;
  unsigned short* op = O + ((size_t)(b * 2048 + qrow)) * 1024 + h * 64;
#pragma unroll
  for (int r = 0; r < 16; ++r) {
    const int d = (r & 3) + 8 * (r >> 2) + 4 * hi;
    op[d] = f2bf(Oa0[r] * inv);
    op[32 + d] = f2bf(Oa1[r] * inv);
  }
}

extern "C" void kernel_launch(void* const* d_in, const int* in_sizes, int n_in,
                              void* d_out, int out_size, void* d_ws, size_t ws_size,
                              hipStream_t stream) {
  const float* x  = (const float*)d_in[0];
  const float* Wq = (const float*)d_in[1];
  const float* bq = (const float*)d_in[2];
  const float* Wk = (const float*)d_in[3];
  const float* bk = (const float*)d_in[4];
  const float* Wv = (const float*)d_in[5];
  const float* bv = (const float*)d_in[6];
  const float* Wo = (const float*)d_in[7];
  const float* bo = (const float*)d_in[8];

  unsigned short* xb  = (unsigned short*)d_ws;
  unsigned short* WqT = xb + (size_t)8192 * 1024;
  unsigned short* WkT = WqT + (size_t)1024 * 1024;
  unsigned short* WvT = WkT + (size_t)1024 * 1024;
  unsigned short* WoT = WvT + (size_t)1024 * 1024;
  unsigned short* Qb  = WoT + (size_t)1024 * 1024;
  unsigned short* Kb  = Qb + (size_t)8192 * 1024;
  unsigned short* Vt  = Kb + (size_t)8192 * 1024;
  unsigned short* Ib  = Vt + (size_t)8192 * 1024;

  k_convert_x<<<4096, 256, 0, stream>>>(x, xb);
  k_transw<<<dim3(256, 4), 256, 0, stream>>>(Wq, Wk, Wv, Wo, WqT, WkT, WvT, WoT);
  k_gemm<0><<<512, 256, 0, stream>>>(xb, WqT, bq, (void*)Qb);
  k_gemm<0><<<512, 256, 0, stream>>>(xb, WkT, bk, (void*)Kb);
  k_gemm<1><<<512, 256, 0, stream>>>(xb, WvT, bv, (void*)Vt);
  k_rope<<<16384, 256, 0, stream>>>(Qb, 1.0f / 32.0f);
  k_rope<<<16384, 256, 0, stream>>>(Kb, 1.0f);
  k_attn<<<1024, 256, 0, stream>>>(Qb, Kb, Vt, Ib);
  k_gemm<2><<<512, 256, 0, stream>>>(Ib, WoT, bo, d_out);
}

// Round 3
// 297.143 us; speedup vs baseline: 1.3988x; 1.0725x over previous
//
#include <hip/hip_runtime.h>

#define DEV __device__ __forceinline__

typedef __attribute__((ext_vector_type(4))) float f32x4;
typedef __attribute__((ext_vector_type(16))) float f32x16;
typedef __attribute__((ext_vector_type(4))) float fl4;
typedef __attribute__((ext_vector_type(8))) __bf16 bf16x8;
typedef __attribute__((ext_vector_type(2))) __bf16 bf16x2;
typedef __attribute__((ext_vector_type(4))) unsigned short us4;
typedef __attribute__((ext_vector_type(8))) unsigned short us8;
typedef __attribute__((ext_vector_type(4))) unsigned int ui4;

DEV unsigned short f2bf(float f) {
  unsigned u = __builtin_bit_cast(unsigned, f);
  u += 0x7fffu + ((u >> 16) & 1u);
  return (unsigned short)(u >> 16);
}
DEV float bf2f(unsigned short h) {
  unsigned u = ((unsigned)h) << 16;
  return __builtin_bit_cast(float, u);
}

DEV void load_lds16(const void* g, void* l) {
  __builtin_amdgcn_global_load_lds(
      (const __attribute__((address_space(1))) void*)g,
      (__attribute__((address_space(3))) void*)l, 16, 0, 0);
}

DEV unsigned pk2(float a, float b) {  // pack 2 fp32 -> 2 bf16
  bf16x2 t;
  t[0] = (__bf16)a; t[1] = (__bf16)b;
  return __builtin_bit_cast(unsigned, t);
}
DEV bf16x8 frag4(unsigned a, unsigned b, unsigned c, unsigned d) {
  ui4 u; u[0] = a; u[1] = b; u[2] = c; u[3] = d;
  return __builtin_bit_cast(bf16x8, u);
}

// ---------------- convert x -> bf16 ----------------
__global__ void k_convert_x(const float* __restrict__ x, unsigned short* __restrict__ xb) {
  size_t i = (size_t)blockIdx.x * 256 + threadIdx.x;
  const float* p = x + i * 8;
  fl4 a = *(const fl4*)p;
  fl4 b = *(const fl4*)(p + 4);
  us8 o;
  o[0] = f2bf(a[0]); o[1] = f2bf(a[1]); o[2] = f2bf(a[2]); o[3] = f2bf(a[3]);
  o[4] = f2bf(b[0]); o[5] = f2bf(b[1]); o[6] = f2bf(b[2]); o[7] = f2bf(b[3]);
  *(us8*)(xb + i * 8) = o;
}

// ---------------- weight transpose -> bf16 ----------------
__global__ void k_transw(const float* __restrict__ W0, const float* __restrict__ W1,
                         const float* __restrict__ W2, const float* __restrict__ W3,
                         unsigned short* __restrict__ T0, unsigned short* __restrict__ T1,
                         unsigned short* __restrict__ T2, unsigned short* __restrict__ T3) {
  const float* W; unsigned short* T;
  switch (blockIdx.y) {
    case 0: W = W0; T = T0; break;
    case 1: W = W1; T = T1; break;
    case 2: W = W2; T = T2; break;
    default: W = W3; T = T3; break;
  }
  __shared__ float tile[64][65];
  int k0 = (blockIdx.x >> 4) * 64, n0 = (blockIdx.x & 15) * 64;
  int tr = threadIdx.x >> 4, tc = (threadIdx.x & 15) * 4;
#pragma unroll
  for (int p = 0; p < 4; ++p) {
    int r = p * 16 + tr;
    fl4 v = *(const fl4*)&W[(size_t)(k0 + r) * 1024 + n0 + tc];
#pragma unroll
    for (int j = 0; j < 4; ++j) tile[r][tc + j] = v[j];
  }
  __syncthreads();
#pragma unroll
  for (int p = 0; p < 4; ++p) {
    int rr = p * 16 + tr;
    us4 o;
#pragma unroll
    for (int j = 0; j < 4; ++j) o[j] = f2bf(tile[tc + j][rr]);
    *(us4*)&T[(size_t)(n0 + rr) * 1024 + k0 + tc] = o;
  }
}

// ---------------- GEMM: 128^2 tile, XCD-swizzled ----------------
template <int MODE>
__global__ __launch_bounds__(256, 3) void k_gemm(const unsigned short* __restrict__ A,
                                                 const unsigned short* __restrict__ Bt,
                                                 const float* __restrict__ bias,
                                                 void* __restrict__ Cout) {
  __shared__ alignas(16) unsigned short As[4096];
  __shared__ alignas(16) unsigned short Bs[4096];
  int tid = threadIdx.x, w = tid >> 6, l = tid & 63;
  int lg = l >> 4, lm = l & 15;
  // XCD swizzle: grid 512 = 8 XCDs x 64; same-XCD chunk = 8 consecutive bm (all bn)
  int sw = (blockIdx.x & 7) * 64 + (blockIdx.x >> 3);
  int bm = sw >> 3, bn = sw & 7;
  int wr = w >> 1, wc = w & 1;
  f32x4 acc[4][4] = {};
  for (int kt = 0; kt < 32; ++kt) {
    int k0 = kt * 32;
#pragma unroll
    for (int p = 0; p < 2; ++p) {
      int cb = (w * 2 + p) * 64;
      int c = cb + l;
      int g = c >> 7, r = c & 127;
      load_lds16(A + (size_t)(bm * 128 + r) * 1024 + k0 + g * 8, As + (size_t)cb * 8);
      load_lds16(Bt + (size_t)(bn * 128 + r) * 1024 + k0 + g * 8, Bs + (size_t)cb * 8);
    }
    __syncthreads();
    bf16x8 af[4], bfr[4];
#pragma unroll
    for (int m = 0; m < 4; ++m)
      af[m] = *(const bf16x8*)&As[(lg * 128 + wr * 64 + m * 16 + lm) * 8];
#pragma unroll
    for (int n = 0; n < 4; ++n)
      bfr[n] = *(const bf16x8*)&Bs[(lg * 128 + wc * 64 + n * 16 + lm) * 8];
    __builtin_amdgcn_s_setprio(1);
#pragma unroll
    for (int m = 0; m < 4; ++m)
#pragma unroll
      for (int n = 0; n < 4; ++n)
        acc[m][n] = __builtin_amdgcn_mfma_f32_16x16x32_bf16(af[m], bfr[n], acc[m][n], 0, 0, 0);
    __builtin_amdgcn_s_setprio(0);
    __syncthreads();
  }
  int row0 = bm * 128 + wr * 64, col0 = bn * 128 + wc * 64;
  if (MODE == 0) {
    unsigned short* C = (unsigned short*)Cout;
#pragma unroll
    for (int n = 0; n < 4; ++n) {
      int col = col0 + n * 16 + lm;
      float bv = bias[col];
#pragma unroll
      for (int m = 0; m < 4; ++m) {
        int row = row0 + m * 16 + lg * 4;
#pragma unroll
        for (int i = 0; i < 4; ++i)
          C[(size_t)(row + i) * 1024 + col] = f2bf(acc[m][n][i] + bv);
      }
    }
  } else if (MODE == 1) {
    unsigned short* Vt = (unsigned short*)Cout;
#pragma unroll
    for (int n = 0; n < 4; ++n) {
      int col = col0 + n * 16 + lm;
      float bv = bias[col];
#pragma unroll
      for (int m = 0; m < 4; ++m) {
        int row = row0 + m * 16 + lg * 4;
        int bb = row >> 11, s = row & 2047;
        us4 o;
#pragma unroll
        for (int i = 0; i < 4; ++i) o[i] = f2bf(acc[m][n][i] + bv);
        *(us4*)&Vt[((size_t)(bb * 1024 + col)) * 2048 + s] = o;
      }
    }
  } else {
    float* C = (float*)Cout;
#pragma unroll
    for (int n = 0; n < 4; ++n) {
      int col = col0 + n * 16 + lm;
      float bv = bias[col];
#pragma unroll
      for (int m = 0; m < 4; ++m) {
        int row = row0 + m * 16 + lg * 4;
#pragma unroll
        for (int i = 0; i < 4; ++i)
          C[(size_t)(row + i) * 1024 + col] = acc[m][n][i] + bv;
      }
    }
  }
}

// ---------------- RoPE ----------------
__global__ void k_rope(unsigned short* __restrict__ X, float scale) {
  int p = blockIdx.x * 256 + threadIdx.x;
  int m = p >> 9, cp = p & 511;
  int t = cp & 31;
  int pos = m & 2047;
  float ang = (float)pos * exp2f(-(float)t * 0.41524101186092029f);
  float sn, cs;
  __sincosf(ang, &sn, &cs);
  unsigned* q = (unsigned*)(X + (size_t)m * 1024 + cp * 2);
  unsigned v = *q;
  float x1 = bf2f((unsigned short)(v & 0xffffu));
  float x2 = bf2f((unsigned short)(v >> 16));
  float o1 = (x1 * cs - x2 * sn) * scale;
  float o2 = (x2 * cs + x1 * sn) * scale;
  *q = ((unsigned)f2bf(o2) << 16) | f2bf(o1);
}

// ---------------- flash attention ----------------
// Q pre-scaled by log2(e)/sqrt(D): S is in log2 units -> p = exp2(s - M) directly.
// Swapped-operand 32x32: lane owns one query; scalar M/L; defer-max (T13, THR=8).
__global__ __launch_bounds__(256, 4) void k_attn(const unsigned short* __restrict__ Q,
                                                 const unsigned short* __restrict__ K,
                                                 const unsigned short* __restrict__ Vt,
                                                 unsigned short* __restrict__ O) {
  __shared__ alignas(16) unsigned short Ks[2][4096];  // [g=kb*4+dc][lane][8]
  __shared__ alignas(16) unsigned short Vs[2][4096];  // [g=m*2+cb][lane][8]
  const int tid = threadIdx.x, w = tid >> 6, l = tid & 63;
  const int lq = l & 31, hi = l >> 5;
  // XCD swizzle: grid 1024 = 8 x 128; same-XCD chunk = 8 full (b,h) groups (K+V ~4MB/L2)
  const int bid = (blockIdx.x & 7) * 128 + (blockIdx.x >> 3);
  const int qt = bid & 15, h = (bid >> 4) & 15, b = bid >> 8;
  const int qrow = qt * 128 + w * 32 + lq;

  const unsigned short* qp = Q + ((size_t)(b * 2048 + qrow)) * 1024 + h * 64 + hi * 8;
  bf16x8 qf[4];
#pragma unroll
  for (int dc = 0; dc < 4; ++dc) qf[dc] = *(const bf16x8*)(qp + dc * 16);

  const unsigned short* Kbase = K + ((size_t)(b * 2048)) * 1024 + h * 64;
  const unsigned short* Vbase = Vt + ((size_t)((b * 16 + h) * 64)) * 2048;

  float M = -1e30f, L = 0.0f;
  f32x16 Oa0 = {}, Oa1 = {};

#pragma unroll
  for (int c = tid; c < 512; c += 256) {
    int g = c >> 6, ll = c & 63;
    load_lds16(Kbase + ((size_t)((g >> 2) * 32 + (ll & 31))) * 1024 + (g & 3) * 16 + (ll >> 5) * 8,
               &Ks[0][c * 8]);
    load_lds16(Vbase + ((size_t)((g & 1) * 32 + (ll & 31))) * 2048 + (g >> 1) * 16 + (ll >> 5) * 8,
               &Vs[0][c * 8]);
  }
  __syncthreads();

  for (int t = 0; t < 32; ++t) {
    const int cur = t & 1;
    if (t + 1 < 32) {
      const int j1 = (t + 1) * 64;
#pragma unroll
      for (int c = tid; c < 512; c += 256) {
        int g = c >> 6, ll = c & 63;
        load_lds16(Kbase + ((size_t)(j1 + (g >> 2) * 32 + (ll & 31))) * 1024 + (g & 3) * 16 + (ll >> 5) * 8,
                   &Ks[cur ^ 1][c * 8]);
        load_lds16(Vbase + ((size_t)((g & 1) * 32 + (ll & 31))) * 2048 + j1 + (g >> 1) * 8 * 2 + (ll >> 5) * 8,
                   &Vs[cur ^ 1][c * 8]);
      }
    }
    // S[key][query]
    f32x16 s0 = {}, s1 = {};
    const unsigned short* Kc = Ks[cur];
    __builtin_amdgcn_s_setprio(1);
#pragma unroll
    for (int dc = 0; dc < 4; ++dc) {
      bf16x8 kf0 = *(const bf16x8*)&Kc[(dc * 64 + l) * 8];
      bf16x8 kf1 = *(const bf16x8*)&Kc[((4 + dc) * 64 + l) * 8];
      s0 = __builtin_amdgcn_mfma_f32_32x32x16_bf16(kf0, qf[dc], s0, 0, 0, 0);
      s1 = __builtin_amdgcn_mfma_f32_32x32x16_bf16(kf1, qf[dc], s1, 0, 0, 0);
    }
    __builtin_amdgcn_s_setprio(0);
    // tile max via max3 chains
    float mx = s0[0];
#pragma unroll
    for (int r = 1; r < 15; r += 2) mx = fmaxf(fmaxf(mx, s0[r]), s0[r + 1]);
    mx = fmaxf(mx, s0[15]);
#pragma unroll
    for (int r = 0; r < 16; r += 2) mx = fmaxf(fmaxf(mx, s1[r]), s1[r + 1]);
    mx = fmaxf(mx, __shfl_xor(mx, 32, 64));
    // defer-max: only rescale when the running max grew by > 8 (log2 units)
    if (!__all(mx - M <= 8.0f)) {
      const float nm = fmaxf(M, mx);
      const float sc = exp2f(M - nm);
      L *= sc;
      Oa0 *= sc;
      Oa1 *= sc;
      M = nm;
    }
    // p = exp2(s - M), in place; bounded by 2^8
#pragma unroll
    for (int r = 0; r < 16; ++r) s0[r] = exp2f(s0[r] - M);
#pragma unroll
    for (int r = 0; r < 16; ++r) s1[r] = exp2f(s1[r] - M);
    // balanced tree sum
    float q8[8];
#pragma unroll
    for (int j = 0; j < 8; ++j) q8[j] = (s0[j] + s0[j + 8]) + (s1[j] + s1[j + 8]);
#pragma unroll
    for (int j = 0; j < 4; ++j) q8[j] += q8[j + 4];
    float ls = (q8[0] + q8[1]) + (q8[2] + q8[3]);
    ls += __shfl_xor(ls, 32, 64);
    L += ls;
    // pack P to bf16 pairs
    unsigned w0[8], w1[8];
#pragma unroll
    for (int j = 0; j < 8; ++j) {
      w0[j] = pk2(s0[2 * j], s0[2 * j + 1]);
      w1[j] = pk2(s1[2 * j], s1[2 * j + 1]);
    }
    // exchange halves with lane^32 to build B-frags
    unsigned ra = __shfl_xor(hi ? w0[0] : w0[2], 32, 64);
    unsigned rb = __shfl_xor(hi ? w0[1] : w0[3], 32, 64);
    unsigned rc = __shfl_xor(hi ? w0[4] : w0[6], 32, 64);
    unsigned rd = __shfl_xor(hi ? w0[5] : w0[7], 32, 64);
    unsigned re = __shfl_xor(hi ? w1[0] : w1[2], 32, 64);
    unsigned rf = __shfl_xor(hi ? w1[1] : w1[3], 32, 64);
    unsigned rg = __shfl_xor(hi ? w1[4] : w1[6], 32, 64);
    unsigned rh = __shfl_xor(hi ? w1[5] : w1[7], 32, 64);
    bf16x8 pf0 = hi ? frag4(ra, rb, w0[2], w0[3]) : frag4(w0[0], w0[1], ra, rb);
    bf16x8 pf1 = hi ? frag4(rc, rd, w0[6], w0[7]) : frag4(w0[4], w0[5], rc, rd);
    bf16x8 pf2 = hi ? frag4(re, rf, w1[2], w1[3]) : frag4(w1[0], w1[1], re, rf);
    bf16x8 pf3 = hi ? frag4(rg, rh, w1[6], w1[7]) : frag4(w1[4], w1[5], rg, rh);
    // O^T[d][query] += V^T[d][key] * P[key][query]
    const unsigned short* Vc = Vs[cur];
    __builtin_amdgcn_s_setprio(1);
    {
      bf16x8 v0 = *(const bf16x8*)&Vc[(0 * 64 + l) * 8];
      bf16x8 v1 = *(const bf16x8*)&Vc[(1 * 64 + l) * 8];
      Oa0 = __builtin_amdgcn_mfma_f32_32x32x16_bf16(v0, pf0, Oa0, 0, 0, 0);
      Oa1 = __builtin_amdgcn_mfma_f32_32x32x16_bf16(v1, pf0, Oa1, 0, 0, 0);
      v0 = *(const bf16x8*)&Vc[(2 * 64 + l) * 8];
      v1 = *(const bf16x8*)&Vc[(3 * 64 + l) * 8];
      Oa0 = __builtin_amdgcn_mfma_f32_32x32x16_bf16(v0, pf1, Oa0, 0, 0, 0);
      Oa1 = __builtin_amdgcn_mfma_f32_32x32x16_bf16(v1, pf1, Oa1, 0, 0, 0);
      v0 = *(const bf16x8*)&Vc[(4 * 64 + l) * 8];
      v1 = *(const bf16x8*)&Vc[(5 * 64 + l) * 8];
      Oa0 = __builtin_amdgcn_mfma_f32_32x32x16_bf16(v0, pf2, Oa0, 0, 0, 0);
      Oa1 = __builtin_amdgcn_mfma_f32_32x32x16_bf16(v1, pf2, Oa1, 0, 0, 0);
      v0 = *(const bf16x8*)&Vc[(6 * 64 + l) * 8];
      v1 = *(const bf16x8*)&Vc[(7 * 64 + l) * 8];
      Oa0 = __builtin_amdgcn_mfma_f32_32x32x16_bf16(v0, pf3, Oa0, 0, 0, 0);
      Oa1 = __builtin_amdgcn_mfma_f32_32x32x16_bf16(v1, pf3, Oa1, 0, 0, 0);
    }
    __builtin_amdgcn_s_setprio(0);
    __syncthreads();
  }
  const float inv = 1.0f / L;
  unsigned short* op = O + ((size_t)(b * 2048 + qrow)) * 1024 + h * 64;
#pragma unroll
  for (int r = 0; r < 16; ++r) {
    const int d = (r & 3) + 8 * (r >> 2) + 4 * hi;
    op[d] = f2bf(Oa0[r] * inv);
    op[32 + d] = f2bf(Oa1[r] * inv);
  }
}

extern "C" void kernel_launch(void* const* d_in, const int* in_sizes, int n_in,
                              void* d_out, int out_size, void* d_ws, size_t ws_size,
                              hipStream_t stream) {
  const float* x  = (const float*)d_in[0];
  const float* Wq = (const float*)d_in[1];
  const float* bq = (const float*)d_in[2];
  const float* Wk = (const float*)d_in[3];
  const float* bk = (const float*)d_in[4];
  const float* Wv = (const float*)d_in[5];
  const float* bv = (const float*)d_in[6];
  const float* Wo = (const float*)d_in[7];
  const float* bo = (const float*)d_in[8];

  unsigned short* xb  = (unsigned short*)d_ws;
  unsigned short* WqT = xb + (size_t)8192 * 1024;
  unsigned short* WkT = WqT + (size_t)1024 * 1024;
  unsigned short* WvT = WkT + (size_t)1024 * 1024;
  unsigned short* WoT = WvT + (size_t)1024 * 1024;
  unsigned short* Qb  = WoT + (size_t)1024 * 1024;
  unsigned short* Kb  = Qb + (size_t)8192 * 1024;
  unsigned short* Vt  = Kb + (size_t)8192 * 1024;
  unsigned short* Ib  = Vt + (size_t)8192 * 1024;

  k_convert_x<<<4096, 256, 0, stream>>>(x, xb);
  k_transw<<<dim3(256, 4), 256, 0, stream>>>(Wq, Wk, Wv, Wo, WqT, WkT, WvT, WoT);
  k_gemm<0><<<512, 256, 0, stream>>>(xb, WqT, bq, (void*)Qb);
  k_gemm<0><<<512, 256, 0, stream>>>(xb, WkT, bk, (void*)Kb);
  k_gemm<1><<<512, 256, 0, stream>>>(xb, WvT, bv, (void*)Vt);
  // Q scale = log2(e)/sqrt(1024): scores come out in log2 units
  k_rope<<<16384, 256, 0, stream>>>(Qb, 1.4426950408889634f / 32.0f);
  k_rope<<<16384, 256, 0, stream>>>(Kb, 1.0f);
  k_attn<<<1024, 256, 0, stream>>>(Qb, Kb, Vt, Ib);
  k_gemm<2><<<512, 256, 0, stream>>>(Ib, WoT, bo, d_out);
}